// Round 5
// baseline (1177.318 us; speedup 1.0000x reference)
//
#include <hip/hip_runtime.h>
#include <math.h>

typedef __attribute__((ext_vector_type(8))) short bf16x8;  // 8 bf16 = 4 VGPR
typedef __attribute__((ext_vector_type(4))) float f32x4;   // MFMA acc

constexpr int LST = 72;    // 64-col bf16 LDS tile row stride (shorts)
constexpr int AST = 520;   // 512-col bf16 LDS tile row stride (shorts)

__device__ __forceinline__ unsigned short f2b(float f) {
    union { float f; unsigned int i; } c; c.f = f;
    unsigned int i = c.i;
    return (unsigned short)((i + 0x7fffu + ((i >> 16) & 1u)) >> 16);  // RNE
}
__device__ __forceinline__ void unpack2(unsigned int v, float& lo, float& hi) {
    union { unsigned int i; float f; } c0, c1;
    c0.i = v << 16; c1.i = v & 0xffff0000u;
    lo = c0.f; hi = c1.f;
}
__device__ __forceinline__ uint2 pack4(float4 v) {
    uint2 pk;
    pk.x = (unsigned int)f2b(v.x) | ((unsigned int)f2b(v.y) << 16);
    pk.y = (unsigned int)f2b(v.z) | ((unsigned int)f2b(v.w) << 16);
    return pk;
}
__device__ __forceinline__ float sigf(float x) { return 1.f / (1.f + __expf(-x)); }
__device__ __forceinline__ float tanhfast(float x) { return 1.f - 2.f / (1.f + __expf(2.f * x)); }

// ---------------- gate GEMM + fused LSTM cell, double-buffered 1-barrier pipeline ----------------
template<int NT>
__device__ __forceinline__ void gate_body(
    int bx, int t, unsigned short* A0l, unsigned short* A1l,
    unsigned short* B0l, unsigned short* B1l,
    const float* __restrict__ A0, const float* __restrict__ A1,
    const float* __restrict__ A2, const float* __restrict__ A3,
    int as0, int as1, int as2, int as3,
    const float* __restrict__ B0, const float* __restrict__ B1,
    const float* __restrict__ B2, const float* __restrict__ B3,
    int bs0, int bs1, int bs2, int bs3,
    const float* __restrict__ b_ih, const float* __restrict__ b_hh,
    const float* __restrict__ c_prev, float* __restrict__ h_out,
    float* __restrict__ c_out, float* __restrict__ h_dup, int K)
{
    constexpr int BM = NT / 4;          // rows per block (64 or 32)
    constexpr int MBLK = 512 / BM;
    constexpr int NA = BM * 16 / NT;    // A float4-chunks per thread (4)
    constexpr int NB = 1024 / NT;       // B float4-chunks per thread (4 or 8)
    const int mb = bx % MBLK, jb = bx / MBLK;
    const int m0 = mb * BM, j0 = jb * 16;
    const int w = t >> 6, lane = t & 63;
    const int col = lane & 15, hi = lane >> 4;
    const int T = K >> 6;

    f32x4 acc[4];
#pragma unroll
    for (int g = 0; g < 4; ++g)
#pragma unroll
        for (int r = 0; r < 4; ++r) acc[g][r] = 0.f;

    float4 ta[NA], tb[NB];

    auto load_tile = [&](int tile) {
        const int kt = tile << 6;
        const int p = kt >> 9, kin = kt & 511;
        const float* ap = (p == 0) ? A0 : (p == 1) ? A1 : (p == 2) ? A2 : A3;
        const int astr   = (p == 0) ? as0 : (p == 1) ? as1 : (p == 2) ? as2 : as3;
        const float* bp = (p == 0) ? B0 : (p == 1) ? B1 : (p == 2) ? B2 : B3;
        const int bstr   = (p == 0) ? bs0 : (p == 1) ? bs1 : (p == 2) ? bs2 : bs3;
#pragma unroll
        for (int k = 0; k < NA; ++k) {
            const int c = t + k * NT, row = c >> 4, q = c & 15;
            ta[k] = *(const float4*)(ap + (astr ? (size_t)(m0 + row) * astr : 0) + kin + q * 4);
        }
#pragma unroll
        for (int k = 0; k < NB; ++k) {
            const int c = t + k * NT, row = c >> 4, q = c & 15;
            const int brow = (row >> 4) * 512 + j0 + (row & 15);
            tb[k] = *(const float4*)(bp + (size_t)brow * bstr + kin + q * 4);
        }
    };
    auto store_tile = [&](unsigned short* Al, unsigned short* Bl) {
#pragma unroll
        for (int k = 0; k < NA; ++k) {
            const int c = t + k * NT, row = c >> 4, q = c & 15;
            *(uint2*)&Al[row * LST + q * 4] = pack4(ta[k]);
        }
#pragma unroll
        for (int k = 0; k < NB; ++k) {
            const int c = t + k * NT, row = c >> 4, q = c & 15;
            *(uint2*)&Bl[row * LST + q * 4] = pack4(tb[k]);
        }
    };
    auto mfma_tile = [&](const unsigned short* Al, const unsigned short* Bl) {
#pragma unroll
        for (int sub = 0; sub < 2; ++sub) {
            const int ko = sub * 32 + hi * 8;
            const bf16x8 af = *(const bf16x8*)&Al[(w * 16 + col) * LST + ko];
#pragma unroll
            for (int g = 0; g < 4; ++g) {
                const bf16x8 bfr = *(const bf16x8*)&Bl[(g * 16 + col) * LST + ko];
                acc[g] = __builtin_amdgcn_mfma_f32_16x16x32_bf16(af, bfr, acc[g], 0, 0, 0);
            }
        }
    };

    load_tile(0);
    store_tile(A0l, B0l);
    load_tile(1);
    __syncthreads();
    int cur = 0;
    for (int tile = 0; tile < T - 1; ++tile) {
        if (cur == 0) { mfma_tile(A0l, B0l); store_tile(A1l, B1l); }
        else          { mfma_tile(A1l, B1l); store_tile(A0l, B0l); }
        if (tile + 2 < T) load_tile(tile + 2);
        __syncthreads();
        cur ^= 1;
    }
    if (cur == 0) mfma_tile(A0l, B0l); else mfma_tile(A1l, B1l);

    // epilogue: fused LSTM cell
    const int j = j0 + col;
    const float bi = b_ih[j]        + b_hh[j];
    const float bf = b_ih[512 + j]  + b_hh[512 + j];
    const float bg = b_ih[1024 + j] + b_hh[1024 + j];
    const float bo = b_ih[1536 + j] + b_hh[1536 + j];
#pragma unroll
    for (int r = 0; r < 4; ++r) {
        const int bidx = m0 + w * 16 + hi * 4 + r;
        const size_t off = (size_t)bidx * 512 + j;
        const float gi = acc[0][r] + bi, gf = acc[1][r] + bf;
        const float gg = acc[2][r] + bg, go = acc[3][r] + bo;
        const float c = c_prev[off];
        const float cn = sigf(gf) * c + sigf(gi) * tanhfast(gg);
        const float hn = sigf(go) * tanhfast(cn);
        h_out[off] = hn;
        c_out[off] = cn;
        if (h_dup) h_dup[off] = hn;
    }
}

// K1: blocks 0..255 layer0 gates; 256..2303 clip f32->bf16 (active rows only); 2304..2305 wc->bf16
__global__ __launch_bounds__(256, 3)
void k1_fused(const float* xt, const float* video, const float* sh2, const float* sh0,
              const float* w_ih0, const float* w_hh0, const float* b_ih0, const float* b_hh0,
              const float* c_prev0, float* h_out0, float* c_out0,
              const float* clip, const int* mask, unsigned short* clip_bf,
              const float* wc, unsigned short* wc_bf)
{
    __shared__ unsigned short lds[18432];   // 36864 B: gate dbuf 4x(64*72)
    __shared__ int s_act[64];
    const int t = threadIdx.x;
    if (blockIdx.x < 256) {
        gate_body<256>(blockIdx.x, t, lds, lds + 4608, lds + 9216, lds + 13824,
                       xt, video, sh2, sh0, 512, 0, 512, 512,
                       w_ih0, w_ih0 + 512, w_ih0 + 1024, w_hh0, 1536, 1536, 1536, 512,
                       b_ih0, b_hh0, c_prev0, h_out0, c_out0, nullptr, 2048);
        return;
    }
    const bool is_wc = blockIdx.x >= 2304;
    const int cb = is_wc ? (blockIdx.x - 2304) : (blockIdx.x - 256);
    const int r0 = cb * 64;
    const float* src = is_wc ? (wc + (size_t)r0 * 512) : (clip + (size_t)r0 * 512);
    unsigned short* dst = is_wc ? (wc_bf + (size_t)r0 * 512) : (clip_bf + (size_t)r0 * 512);
    if (t < 64) s_act[t] = is_wc ? 1 : mask[r0 + t];
    __syncthreads();
#pragma unroll
    for (int g = 0; g < 4; ++g) {
        float4 tmp[8];
#pragma unroll
        for (int u = 0; u < 8; ++u) {
            const int c = t + (g * 8 + u) * 256, row = c >> 7, q = c & 127;
            tmp[u] = make_float4(0.f, 0.f, 0.f, 0.f);
            if (s_act[row]) tmp[u] = *(const float4*)(src + (size_t)row * 512 + q * 4);
        }
#pragma unroll
        for (int u = 0; u < 8; ++u) {
            const int c = t + (g * 8 + u) * 256, row = c >> 7, q = c & 127;
            if (s_act[row]) *(uint2*)&dst[(size_t)row * 512 + q * 4] = pack4(tmp[u]);
        }
    }
}

__global__ __launch_bounds__(128, 4)
void gate_layer(const float* A0, const float* A1, const float* A2,
                int as0, int as1, int as2,
                const float* w_ih, const float* w_hh,
                const float* b_ih, const float* b_hh,
                const float* c_prev, float* h_out, float* c_out, float* h_dup, int K)
{
    __shared__ unsigned short lds[13824];   // A dbuf 2x(32*72) + B dbuf 2x(64*72)
    gate_body<128>(blockIdx.x, threadIdx.x, lds, lds + 2304, lds + 4608, lds + 9216,
                   A0, A1, A2, nullptr, as0, as1, as2, 0,
                   w_ih, w_ih + 512, w_hh, nullptr, 1024, 1024, 512, 0,
                   b_ih, b_hh, c_prev, h_out, c_out, h_dup, K);
}

// att_h = h1 @ wh^T + bh, once. grid 64 x 256thr, block handles 8 batches.
__global__ __launch_bounds__(256)
void atth_kernel(const float* __restrict__ h1, const float* __restrict__ wh,
                 const float* __restrict__ bh, float* __restrict__ atth)
{
    __shared__ float sh[8 * 512];
    const int t = threadIdx.x, b0 = blockIdx.x * 8;
    for (int i = t; i < 8 * 512; i += 256) sh[i] = h1[(size_t)b0 * 512 + i];
    __syncthreads();
    const int a = t & 127, g = t >> 7;
    const float4* wr4 = (const float4*)(wh + (size_t)a * 512);
    float acc[4] = {0.f, 0.f, 0.f, 0.f};
    for (int k4 = 0; k4 < 128; ++k4) {
        const float4 wv = wr4[k4];
#pragma unroll
        for (int bi = 0; bi < 4; ++bi) {
            const float* hp = sh + (g * 4 + bi) * 512 + k4 * 4;
            acc[bi] += wv.x * hp[0] + wv.y * hp[1] + wv.z * hp[2] + wv.w * hp[3];
        }
    }
    const float bias = bh[a];
#pragma unroll
    for (int bi = 0; bi < 4; ++bi)
        atth[(size_t)(b0 + g * 4 + bi) * 128 + a] = acc[bi] + bias;
}

// K3: per 32-row block: scores[m] = ba + sum_n wa[n]*tanh((clip_bf@wc_bf^T)[m,n] + bc[n] + atth[b,n])
__global__ __launch_bounds__(256, 2)
void score_kernel(const unsigned short* __restrict__ clip_bf, const unsigned short* __restrict__ wc_bf,
                  const float* __restrict__ bc, const float* __restrict__ atth,
                  const float* __restrict__ wa, const float* __restrict__ ba,
                  const int* __restrict__ mask, float* __restrict__ scores)
{
    __shared__ unsigned short Ab[32 * AST];   // 33280 B
    __shared__ unsigned short Bt[128 * LST];  // 18432 B (aliased as s_part in epilogue)
    __shared__ float s_atth[128], s_wa[128];
    __shared__ int s_act[32], s_any;
    const int t = threadIdx.x;
    const int m0 = blockIdx.x * 32, b = blockIdx.x >> 3;

    if (t < 32) s_act[t] = mask[m0 + t];
    if (t < 128) s_wa[t] = wa[t];
    __syncthreads();
    if (t == 0) { int n = 0; for (int i = 0; i < 32; ++i) n += s_act[i]; s_any = n; }
    if (t < 128) s_atth[t] = atth[(size_t)b * 128 + t];
    __syncthreads();
    if (!s_any) return;

    // stage A (bf16, active rows only)
    uint4 av[8];
#pragma unroll
    for (int u = 0; u < 8; ++u) {
        const int c = t + u * 256, row = c >> 6, q = c & 63;
        if (s_act[row]) av[u] = *(const uint4*)&clip_bf[(size_t)(m0 + row) * 512 + q * 8];
    }
#pragma unroll
    for (int u = 0; u < 8; ++u) {
        const int c = t + u * 256, row = c >> 6, q = c & 63;
        if (s_act[row]) *(uint4*)&Ab[row * AST + q * 8] = av[u];
    }

    const int w = t >> 6, lane = t & 63;
    const int col = lane & 15, hi = lane >> 4;
    f32x4 acc[2][2];
#pragma unroll
    for (int i = 0; i < 2; ++i)
#pragma unroll
        for (int j = 0; j < 2; ++j)
#pragma unroll
            for (int r = 0; r < 4; ++r) acc[i][j][r] = 0.f;

    for (int kt = 0; kt < 8; ++kt) {
        uint4 bv[4];
#pragma unroll
        for (int u = 0; u < 4; ++u) {
            const int c = t + u * 256, row = c >> 3, q = c & 7;
            bv[u] = *(const uint4*)&wc_bf[(size_t)row * 512 + kt * 64 + q * 8];
        }
        __syncthreads();   // prev tile's Bt reads done; kt=0: A-writes ordered before too
#pragma unroll
        for (int u = 0; u < 4; ++u) {
            const int c = t + u * 256, row = c >> 3, q = c & 7;
            *(uint4*)&Bt[row * LST + q * 8] = bv[u];
        }
        __syncthreads();
        const int k0 = kt * 64;
#pragma unroll
        for (int sub = 0; sub < 2; ++sub) {
            const int ko = sub * 32 + hi * 8;
            bf16x8 af[2], bfr[2];
            af[0] = *(const bf16x8*)&Ab[col * AST + k0 + ko];
            af[1] = *(const bf16x8*)&Ab[(16 + col) * AST + k0 + ko];
            bfr[0] = *(const bf16x8*)&Bt[(w * 32 + col) * LST + ko];
            bfr[1] = *(const bf16x8*)&Bt[(w * 32 + 16 + col) * LST + ko];
#pragma unroll
            for (int i = 0; i < 2; ++i)
#pragma unroll
                for (int j = 0; j < 2; ++j)
                    acc[i][j] = __builtin_amdgcn_mfma_f32_16x16x32_bf16(af[i], bfr[j], acc[i][j], 0, 0, 0);
        }
    }
    __syncthreads();
    float* s_part = (float*)Bt;   // 32 x 64
    float p[2][4];
#pragma unroll
    for (int i = 0; i < 2; ++i)
#pragma unroll
        for (int r = 0; r < 4; ++r) p[i][r] = 0.f;
#pragma unroll
    for (int j = 0; j < 2; ++j) {
        const int n = w * 32 + j * 16 + col;
        const float base = bc[n] + s_atth[n];
        const float wan = s_wa[n];
#pragma unroll
        for (int i = 0; i < 2; ++i)
#pragma unroll
            for (int r = 0; r < 4; ++r)
                p[i][r] += wan * tanhfast(acc[i][j][r] + base);
    }
#pragma unroll
    for (int i = 0; i < 2; ++i)
#pragma unroll
        for (int r = 0; r < 4; ++r) {
            const int m = i * 16 + hi * 4 + r;
            s_part[m * 64 + w * 16 + col] = p[i][r];
        }
    __syncthreads();
    if (t < 32) {
        float s = ba[0];
        for (int k = 0; k < 64; ++k) s += s_part[t * 64 + k];
        scores[m0 + t] = s;
    }
}

// K4: per-batch masked softmax over scores + weighted sum of clip_bf
__global__ __launch_bounds__(256)
void wsum_kernel(const float* __restrict__ scores, const int* __restrict__ mask,
                 const unsigned short* __restrict__ clip_bf, float* __restrict__ att_res)
{
    __shared__ float s_red[8];
    __shared__ float s_w[256];
    __shared__ int s_idx[256];
    __shared__ int s_cnt;
    const int b = blockIdx.x, t = threadIdx.x;
    if (t == 0) s_cnt = 0;
    const int act = mask[(size_t)b * 256 + t];
    const float sc = scores[(size_t)b * 256 + t];
    __syncthreads();

    float v = act ? sc : -3.4e38f;
    for (int off = 32; off > 0; off >>= 1) v = fmaxf(v, __shfl_down(v, off));
    if ((t & 63) == 0) s_red[t >> 6] = v;
    __syncthreads();
    if (t == 0) s_red[4] = fmaxf(fmaxf(s_red[0], s_red[1]), fmaxf(s_red[2], s_red[3]));
    __syncthreads();
    const float mx = s_red[4];
    const float e = act ? __expf(sc - mx) : 0.f;
    float sv = e;
    for (int off = 32; off > 0; off >>= 1) sv += __shfl_down(sv, off);
    if ((t & 63) == 0) s_red[t >> 6] = sv;
    __syncthreads();
    if (t == 0) s_red[5] = s_red[0] + s_red[1] + s_red[2] + s_red[3];
    __syncthreads();
    const float wgt = e / s_red[5];
    if (wgt != 0.f) {
        const int pos = atomicAdd(&s_cnt, 1);
        s_idx[pos] = t;
        s_w[pos] = wgt;
    }
    __syncthreads();
    const int cnt = s_cnt;

    float a0 = 0.f, a1 = 0.f;
    const unsigned short* cbb = clip_bf + (size_t)b * (256 * 512);
    int i = 0;
    for (; i + 8 <= cnt; i += 8) {
        unsigned int vv[8]; float ww[8];
#pragma unroll
        for (int u = 0; u < 8; ++u) {
            vv[u] = *(const unsigned int*)&cbb[s_idx[i + u] * 512 + 2 * t];
            ww[u] = s_w[i + u];
        }
#pragma unroll
        for (int u = 0; u < 8; ++u) {
            float lo, hi2;
            unpack2(vv[u], lo, hi2);
            a0 += ww[u] * lo;
            a1 += ww[u] * hi2;
        }
    }
    for (; i < cnt; ++i) {
        float lo, hi2;
        unpack2(*(const unsigned int*)&cbb[s_idx[i] * 512 + 2 * t], lo, hi2);
        a0 += s_w[i] * lo;
        a1 += s_w[i] * hi2;
    }
    float2 o; o.x = a0; o.y = a1;
    *(float2*)&att_res[(size_t)b * 512 + 2 * t] = o;
}

extern "C" void kernel_launch(void* const* d_in, const int* in_sizes, int n_in,
                              void* d_out, int out_size, void* d_ws, size_t ws_size,
                              hipStream_t stream) {
    typedef const float* cf;
    cf xt      = (cf)d_in[0];
    cf video   = (cf)d_in[1];
    cf event   = (cf)d_in[2];
    cf clip    = (cf)d_in[3];
    const int* mask = (const int*)d_in[4];
    cf state_h = (cf)d_in[5];
    cf state_c = (cf)d_in[6];
    cf w_ih0 = (cf)d_in[7],  w_hh0 = (cf)d_in[8],  b_ih0 = (cf)d_in[9],  b_hh0 = (cf)d_in[10];
    cf w_ih1 = (cf)d_in[11], w_hh1 = (cf)d_in[12], b_ih1 = (cf)d_in[13], b_hh1 = (cf)d_in[14];
    cf w_ih2 = (cf)d_in[15], w_hh2 = (cf)d_in[16], b_ih2 = (cf)d_in[17], b_hh2 = (cf)d_in[18];
    cf wc = (cf)d_in[19], bc = (cf)d_in[20];
    cf wh = (cf)d_in[21], bh = (cf)d_in[22];
    cf wa = (cf)d_in[23], ba = (cf)d_in[24];

    float* out = (float*)d_out;
    const int BH = 512 * 512;
    float* new_h = out + BH;       // [3,B,H]
    float* new_c = out + 4 * BH;   // [3,B,H]
    float* h1 = new_h + BH;

    unsigned short* clip_bf = (unsigned short*)d_ws;                      // 128 MB bf16
    unsigned short* wc_bf   = (unsigned short*)((char*)d_ws + (128u << 20)); // 128 KB
    float* scores           = (float*)((char*)d_ws + (129u << 20));       // 512 KB
    float* atth             = (float*)((char*)d_ws + (130u << 20));       // 256 KB
    float* att_res          = (float*)((char*)d_ws + (131u << 20));       // 1 MB

    // K1: layer0 gates (0-255) || clip->bf16 active rows (256-2303) || wc->bf16 (2304-2305)
    k1_fused<<<2306, 256, 0, stream>>>(
        xt, video, state_h + 2 * BH, state_h,
        w_ih0, w_hh0, b_ih0, b_hh0,
        state_c, new_h, new_c,
        clip, mask, clip_bf, wc, wc_bf);

    // K2: layer1 gates (A = [event | h0 | sh1])
    gate_layer<<<512, 128, 0, stream>>>(
        event, new_h, state_h + BH, 512, 512, 512,
        w_ih1, w_hh1, b_ih1, b_hh1,
        state_c + BH, new_h + BH, new_c + BH, nullptr, 1536);

    // K2.5: att_h (needs h1)
    atth_kernel<<<64, 256, 0, stream>>>(h1, wh, bh, atth);

    // K3: scores (GEMM vs wc_bf, epilogue tanh-dot; no att matrix)
    score_kernel<<<4096, 256, 0, stream>>>(clip_bf, wc_bf, bc, atth, wa, ba, mask, scores);

    // K4: softmax + weighted clip sum
    wsum_kernel<<<512, 256, 0, stream>>>(scores, mask, clip_bf, att_res);

    // K5: layer2 gates (A = [att_res | h1 | sh2]); h2 dual-written to out[0:BH]
    gate_layer<<<512, 128, 0, stream>>>(
        att_res, new_h + BH, state_h + 2 * BH, 512, 512, 512,
        w_ih2, w_hh2, b_ih2, b_hh2,
        state_c + 2 * BH, new_h + 2 * BH, new_c + 2 * BH, out, 1536);
}